// Round 6
// baseline (329.085 us; speedup 1.0000x reference)
//
#include <hip/hip_runtime.h>
#include <math.h>

// Problem constants
#define NCELLS 131072
#define IND 64
#define HD 128
#define OUTD 64
#define NF 8
#define FS 16384
#define DC 4096
#define TB 64             // cells per fused block
#define NBLK (NCELLS/TB)  // 2048
#define NTH 512
#define NREP 4            // atomic replication factor
#define NT (NCELLS*HD)

typedef __bf16 bf16x8 __attribute__((ext_vector_type(8)));
typedef float f32x4 __attribute__((ext_vector_type(4)));
typedef unsigned short us8 __attribute__((ext_vector_type(8)));

#define MFMA(a,b,c) __builtin_amdgcn_mfma_f32_16x16x32_bf16(a,b,c,0,0,0)

// ---- workspace layout ----
// Weights FRAGMENT-SWIZZLED (r2): fragment = contiguous 1KB; wave loads one
// fragment with a single coalesced dwordx4 at base + frag*512 + lane*8.
#define WS_W1H 0          // [256][128]  (KT=4, 64 frags)
#define WS_W2F 32768      // [64][256]   (KT=8, 32 frags)
#define WS_WIH 49152      // [384][64]   (KT=2, 48 frags)
#define WS_WHH 73728      // [384][128]  (KT=4, 96 frags)
#define WS_U_TOTAL 122880
// float region at (float*)((ushort*)ws + WS_U_TOTAL):
#define WF_B1   0         // [256] = b1 + x @ W1x.T
#define WF_B2   256       // [64]
#define WF_WT   320       // [384] = Wih[:,64] fp32
#define WF_FSUM 704       // [NREP][8][128]
#define WF_WSUM 4800      // [NREP][64]
#define WF_SE   5056
#define WF_TS   5060
#define WF_TOTAL 5064
#define WS_NH_OFF 266240  // align256; newh scratch (fp16)

// ---- LDS layout (ushort units), total 27136 us = 54272 B -> 3 blocks/CU ----
// Strides 138/266 (odd bank shift 5) break the 4-way conflicts of 136/264.
#define L_SC    0         // [64][138] us : h bf16
#define L_SH1   8832      // [64][266] us : relu(h1) bf16  (region ends 25856)
#define L_SOF_F 4416      // float idx (us 8832): [64][68] f32 out (overlays sh1)
#define L_SOB   17536     // [64][72] us : out bf16 (overlays sh1 tail)
#define L_ST_F  12928     // us 25856: [64] f32 t
#define L_SE_F  12992     // us 26112... [64] f32 e^t
#define L_WSCR_F 13056    // [512] f32 reduction scratch
#define L_TOT   27136

__device__ __forceinline__ unsigned short f2bf(float f) {
    unsigned u = __builtin_bit_cast(unsigned, f);
    return (unsigned short)((u + 0x7FFFu + ((u >> 16) & 1u)) >> 16);
}
__device__ __forceinline__ bf16x8 ld8(const unsigned short* p) {
    return __builtin_bit_cast(bf16x8, *(const us8*)p);
}
__device__ __forceinline__ float sigm(float v) {
    return __builtin_amdgcn_rcpf(1.f + __builtin_amdgcn_exp2f(-1.44269504f * v));
}
__device__ __forceinline__ float tanh_fast(float v) {
    return 1.f - 2.f * __builtin_amdgcn_rcpf(1.f + __builtin_amdgcn_exp2f(2.88539008f * v));
}

// ---- per-launch weight conversion fp32 -> bf16 fragment-swizzled ----
__global__ __launch_bounds__(256) void convert_kernel(
    const float* __restrict__ x,
    const float* __restrict__ W1a, const float* __restrict__ b1a,
    const float* __restrict__ W2a, const float* __restrict__ b2a,
    const float* __restrict__ W1g, const float* __restrict__ b1g,
    const float* __restrict__ W2g, const float* __restrict__ b2g,
    const float* __restrict__ Wih, const float* __restrict__ Whh,
    unsigned short* __restrict__ wsu, float* __restrict__ wsf)
{
    int i = blockIdx.x * 256 + threadIdx.x;
    if (i < 32768) {                         // W1H, KT=4
        int frag = i >> 9, r = i & 511;
        int lane = r >> 3, e = r & 7;
        int col = (frag >> 2)*16 + (lane & 15);
        int k   = (frag & 3)*32 + (lane >> 4)*8 + e;
        float v = (col < 128) ? W1a[col*192 + 64 + k] : W1g[(col-128)*192 + 64 + k];
        wsu[WS_W1H + i] = f2bf(v); return;
    }
    int j = i - 32768;
    if (j < 16384) {                         // W2F, KT=8
        int frag = j >> 9, r = j & 511;
        int lane = r >> 3, e = r & 7;
        int col = (frag >> 3)*16 + (lane & 15);
        int k   = (frag & 7)*32 + (lane >> 4)*8 + e;
        float v = (k < 128) ? W2a[col*128 + k] : -W2g[col*128 + (k-128)];
        wsu[WS_W2F + j] = f2bf(v); return;
    }
    j -= 16384;
    if (j < 24576) {                         // WIH (out-cols), KT=2
        int frag = j >> 9, r = j & 511;
        int lane = r >> 3, e = r & 7;
        int col = (frag >> 1)*16 + (lane & 15);
        int k   = (frag & 1)*32 + (lane >> 4)*8 + e;
        wsu[WS_WIH + j] = f2bf(Wih[col*65 + k]); return;
    }
    j -= 24576;
    if (j < 49152) {                         // WHH, KT=4
        int frag = j >> 9, r = j & 511;
        int lane = r >> 3, e = r & 7;
        int col = (frag >> 2)*16 + (lane & 15);
        int k   = (frag & 3)*32 + (lane >> 4)*8 + e;
        wsu[WS_WHH + j] = f2bf(Whh[col*128 + k]); return;
    }
    j -= 49152;
    if (j < 256) {                           // b1' = b1 + x @ W1x.T  (fp32)
        const float* wr = (j < 128) ? (W1a + j*192) : (W1g + (size_t)(j-128)*192);
        float base = (j < 128) ? b1a[j] : b1g[j-128];
        float dot = 0.f;
        #pragma unroll 8
        for (int k = 0; k < 64; ++k) dot += x[k] * wr[k];
        wsf[WF_B1 + j] = base + dot; return;
    }
    j -= 256;
    if (j < 64)  { wsf[WF_B2 + j] = b2a[j] - b2g[j]; return; }
    j -= 64;
    if (j < 384) { wsf[WF_WT + j] = Wih[j*65 + 64]; return; }
}

// ---- fused per-cell pipeline, TB=64, 8 waves, pinned B prefetch ----
// launch_bounds (512,3): VGPR cap ~170 (loose; tight caps spilled in r2).
__global__ __launch_bounds__(NTH, 3) void fused_cell_kernel(
    const float* __restrict__ hiddens,
    const float* __restrict__ bih, const float* __restrict__ bhh,
    const unsigned short* __restrict__ wsu, const float* __restrict__ wsf,
    unsigned short* __restrict__ nh16, float* __restrict__ nhf,
    float* __restrict__ fsum, float* __restrict__ wsum,
    float* __restrict__ sumexp, float* __restrict__ tsum, int mode)
{
    __shared__ __align__(16) unsigned short sm[L_TOT];
    float* smf = (float*)sm;

    const int tid = threadIdx.x;
    const int cell0 = blockIdx.x * TB;
    const int w = tid >> 6, lane = tid & 63;
    const int q = lane >> 4, cL = lane & 15;
    const int rep = blockIdx.x & (NREP-1);

    // ---- prefetch GEMM1 B frags; sched_barrier pins the issue point so the
    //      loads cannot sink to their use (r5: compiler sank them, VGPR=64) ----
    bf16x8 pB1[8];
    {
        const unsigned short* wp = wsu + WS_W1H + (w*2)*4*512 + lane*8;
        #pragma unroll
        for (int k = 0; k < 8; ++k) pB1[k] = ld8(wp + k*512);
    }
    __builtin_amdgcn_sched_barrier(0);

    // ---- phase 0: stage h bf16 into sc [64][138] ----
    for (int idx = tid; idx < TB*(HD/4); idx += NTH) {
        int c = idx >> 5, k4 = idx & 31;
        float4 v = ((const float4*)hiddens)[(size_t)(cell0+c)*(HD/4) + k4];
        unsigned p0 = (unsigned)f2bf(v.x) | ((unsigned)f2bf(v.y) << 16);
        unsigned p1 = (unsigned)f2bf(v.z) | ((unsigned)f2bf(v.w) << 16);
        *(unsigned*)&sm[L_SC + c*138 + k4*4]     = p0;
        *(unsigned*)&sm[L_SC + c*138 + k4*4 + 2] = p1;
    }
    __syncthreads();

    // ---- phase 1: GEMM1 (pinned prefetch of GEMM2 B at top) ----
    bf16x8 pB2[8];
    {
        const unsigned short* wp = wsu + WS_W2F + (w & 3)*8*512 + lane*8;
        #pragma unroll
        for (int k = 0; k < 8; ++k) pB2[k] = ld8(wp + k*512);
    }
    __builtin_amdgcn_sched_barrier(0);
    #pragma unroll
    for (int ct = 0; ct < 2; ++ct) {
        const int col = w*32 + ct*16 + cL;
        const float bias = wsf[WF_B1 + col];
        f32x4 acc[4];
        #pragma unroll
        for (int m = 0; m < 4; ++m) acc[m] = (f32x4){bias,bias,bias,bias};
        #pragma unroll
        for (int k = 0; k < 4; ++k) {
            bf16x8 B = pB1[ct*4 + k];
            #pragma unroll
            for (int m = 0; m < 4; ++m) {
                bf16x8 A = ld8(&sm[L_SC + (m*16+cL)*138 + k*32 + q*8]);
                acc[m] = MFMA(A, B, acc[m]);
            }
        }
        #pragma unroll
        for (int m = 0; m < 4; ++m)
            #pragma unroll
            for (int r = 0; r < 4; ++r)
                sm[L_SH1 + (m*16+q*4+r)*266 + col] = f2bf(fmaxf(acc[m][r], 0.f));
    }
    __syncthreads();

    // ---- phase 2: GEMM2 (pinned prefetch of GRU gi B at top) ----
    bf16x8 pGi[6];
    {
        const unsigned short* wiB = wsu + WS_WIH + lane*8;
        #pragma unroll
        for (int k = 0; k < 2; ++k) {
            pGi[k]   = ld8(wiB + ((     w)*2 + k)*512);
            pGi[2+k] = ld8(wiB + (( 8 + w)*2 + k)*512);
            pGi[4+k] = ld8(wiB + ((16 + w)*2 + k)*512);
        }
    }
    __builtin_amdgcn_sched_barrier(0);
    f32x4 o0, o1;
    {
        const int Mt0 = (w >> 2)*2, Mt1 = Mt0 + 1;
        const float bias = wsf[WF_B2 + (w & 3)*16 + cL];
        o0 = (f32x4){bias,bias,bias,bias}; o1 = o0;
        #pragma unroll
        for (int k = 0; k < 8; ++k) {
            bf16x8 B  = pB2[k];
            bf16x8 A0 = ld8(&sm[L_SH1 + (Mt0*16+cL)*266 + k*32 + q*8]);
            o0 = MFMA(A0, B, o0);
            bf16x8 A1 = ld8(&sm[L_SH1 + (Mt1*16+cL)*266 + k*32 + q*8]);
            o1 = MFMA(A1, B, o1);
        }
    }
    __syncthreads();   // all sh1 reads done; overlay region now writable

    // ---- phase 2b: out tiles into overlay (sof fp32, sob bf16) ----
    {
        const int col = (w & 3)*16 + cL;
        const int Mt0 = (w >> 2)*2, Mt1 = Mt0 + 1;
        #pragma unroll
        for (int r = 0; r < 4; ++r) {
            int r0 = Mt0*16 + q*4 + r, r1 = Mt1*16 + q*4 + r;
            smf[L_SOF_F + r0*68 + col] = o0[r];
            sm [L_SOB   + r0*72 + col] = f2bf(o0[r]);
            smf[L_SOF_F + r1*68 + col] = o1[r];
            sm [L_SOB   + r1*72 + col] = f2bf(o1[r]);
        }
    }
    __syncthreads();

    // ---- phase 3: t = mean(out^2), e^t ----
    {
        const int c = tid >> 3, g = tid & 7;
        f32x4 a = *(const f32x4*)&smf[L_SOF_F + c*68 + g*8];
        f32x4 b = *(const f32x4*)&smf[L_SOF_F + c*68 + g*8 + 4];
        float s = a[0]*a[0] + a[1]*a[1] + a[2]*a[2] + a[3]*a[3]
                + b[0]*b[0] + b[1]*b[1] + b[2]*b[2] + b[3]*b[3];
        s += __shfl_xor(s, 1);
        s += __shfl_xor(s, 2);
        s += __shfl_xor(s, 4);
        if (g == 0) {
            float t = s * (1.0f/OUTD);
            smf[L_ST_F + c] = t;
            smf[L_SE_F + c] = __builtin_amdgcn_exp2f(t * 1.44269504f);
        }
    }
    __syncthreads();

    // ---- phase 4: GRU gates, merged 4-M-tile pass ----
    const int fidx = (int)(blockIdx.x >> 8);
    {
        const int j = w*16 + cL;
        const float bR = bih[j]      + bhh[j];
        const float bZ = bih[HD+j]   + bhh[HD+j];
        const float bI = bih[2*HD+j];
        const float bH = bhh[2*HD+j];
        const float wtR = wsf[WF_WT + j];
        const float wtZ = wsf[WF_WT + HD + j];
        const float wtI = wsf[WF_WT + 2*HD + j];
        f32x4 R[4], Z[4], I[4], H[4];
        #pragma unroll
        for (int m = 0; m < 4; ++m) {
            R[m] = (f32x4){bR,bR,bR,bR}; Z[m] = (f32x4){bZ,bZ,bZ,bZ};
            I[m] = (f32x4){bI,bI,bI,bI}; H[m] = (f32x4){bH,bH,bH,bH};
        }
        // fp32 h_old loads from global (replaces bf16 LDS hold: removes that
        // rounding term, offsetting the fp16 scratch error)
        float hold[16];
        #pragma unroll
        for (int m = 0; m < 4; ++m)
            #pragma unroll
            for (int r = 0; r < 4; ++r)
                hold[m*4+r] = hiddens[(size_t)(cell0 + m*16 + q*4 + r)*HD + j];
        #pragma unroll
        for (int k = 0; k < 2; ++k) {        // gi: K=64
            bf16x8 Br = pGi[k], Bz = pGi[2+k], Bi = pGi[4+k];
            #pragma unroll
            for (int m = 0; m < 4; ++m) {
                bf16x8 A = ld8(&sm[L_SOB + (m*16+cL)*72 + k*32 + q*8]);
                R[m] = MFMA(A, Br, R[m]);
                Z[m] = MFMA(A, Bz, Z[m]);
                I[m] = MFMA(A, Bi, I[m]);
            }
        }
        const unsigned short* whB = wsu + WS_WHH + lane*8;
        #pragma unroll
        for (int k = 0; k < 4; ++k) {        // gh: K=128
            bf16x8 Br = ld8(whB + ((     w)*4 + k)*512);
            bf16x8 Bz = ld8(whB + (( 8 + w)*4 + k)*512);
            bf16x8 Bn = ld8(whB + ((16 + w)*4 + k)*512);
            #pragma unroll
            for (int m = 0; m < 4; ++m) {
                bf16x8 A = ld8(&sm[L_SC + (m*16+cL)*138 + k*32 + q*8]);
                R[m] = MFMA(A, Br, R[m]);
                Z[m] = MFMA(A, Bz, Z[m]);
                H[m] = MFMA(A, Bn, H[m]);
            }
        }
        float colsum = 0.f;
        #pragma unroll
        for (int m = 0; m < 4; ++m) {
            #pragma unroll
            for (int r = 0; r < 4; ++r) {
                const int row = m*16 + q*4 + r;
                const float tv = smf[L_ST_F + row];
                const float rr = sigm(R[m][r] + tv*wtR);
                const float zz = sigm(Z[m][r] + tv*wtZ);
                const float nn = tanh_fast(I[m][r] + tv*wtI + rr*H[m][r]);
                const float hv = (1.f - zz)*nn + zz*hold[m*4+r];
                const size_t g = (size_t)(cell0+row)*HD + j;
                if (mode) nh16[g] = __builtin_bit_cast(unsigned short, (_Float16)hv);
                else      nhf[g]  = hv;
                colsum += hv;
            }
        }
        colsum += __shfl_xor(colsum, 16);
        colsum += __shfl_xor(colsum, 32);
        if (q == 0) unsafeAtomicAdd(&fsum[(rep*NF + fidx)*HD + j], colsum);
    }

    // ---- phase 5: softmax-weighted sums ----
    {
        const int col = tid & 63, cg = tid >> 6;
        float wacc = 0.f;
        #pragma unroll
        for (int c8 = 0; c8 < 8; ++c8) {
            const int c = cg*8 + c8;
            wacc += smf[L_SE_F + c] * smf[L_SOF_F + c*68 + col];
        }
        smf[L_WSCR_F + cg*64 + col] = wacc;
    }
    __syncthreads();
    if (tid < 64) {
        float wacc = 0.f;
        #pragma unroll
        for (int g = 0; g < 8; ++g) wacc += smf[L_WSCR_F + g*64 + tid];
        unsafeAtomicAdd(&wsum[rep*64 + tid], wacc);
        float e = smf[L_SE_F + tid];
        float t = smf[L_ST_F + tid];
        #pragma unroll
        for (int d = 1; d < 64; d <<= 1) { e += __shfl_xor(e, d); t += __shfl_xor(t, d); }
        if (tid == 0) { unsafeAtomicAdd(&sumexp[rep], e); unsafeAtomicAdd(&tsum[rep], t); }
    }
}

// ---- faction sync: dst = a*h + b[j]; fp16 scratch read (half traffic) ----
#define TBF 64
__global__ __launch_bounds__(256) void faction_kernel(
    const unsigned short* __restrict__ src16, float* __restrict__ dst,
    const float* __restrict__ fsum, const int* __restrict__ step,
    const float* __restrict__ Wo, const float* __restrict__ bo,
    const float* __restrict__ wsum, const float* __restrict__ sumexp,
    const float* __restrict__ tsum, float* __restrict__ d_out, int mode)
{
    __shared__ float bnon[HD], bdeb[HD];
    const int cell0 = blockIdx.x * TBF;
    const int f = blockIdx.x >> 8;            // 256 blocks per faction
    if (threadIdx.x < HD) {
        const int jc = threadIdx.x;
        float s = 0.f, fm_s = 0.f;
        #pragma unroll
        for (int rr = 0; rr < NREP; ++rr) {
            #pragma unroll
            for (int ff = 0; ff < NF; ++ff) s += fsum[(rr*NF+ff)*HD + jc];
            fm_s += fsum[(rr*NF+f)*HD + jc];
        }
        const float go = s * (1.0f/NCELLS);
        const float fm = fm_s * (1.0f/FS);
        bnon[jc] = 0.15f*fm;
        bdeb[jc] = 0.1275f*fm + 0.15f*go;
    }
    __syncthreads();
    const bool debate = (step[0] > 5) && ((cell0 & (FS-1)) < DC);  // uniform per block
    const float a = debate ? 0.7225f : 0.85f;
    const float* brow = debate ? bdeb : bnon;
    float* drow = dst + (size_t)cell0*HD;
    if (mode) {
        const unsigned short* srow = src16 + (size_t)cell0*HD;
        #pragma unroll
        for (int it = 0; it < 4; ++it) {
            const int e0 = (threadIdx.x + it*256) * 8;   // 16B-aligned, cell-local
            us8 v = *(const us8*)(srow + e0);
            const int jb = e0 & 127;
            #pragma unroll
            for (int u = 0; u < 8; ++u) {
                float hv = (float)__builtin_bit_cast(_Float16, (unsigned short)v[u]);
                drow[e0 + u] = a*hv + brow[jb + u];
            }
        }
    } else {                                   // fallback: fp32 in-place
        #pragma unroll
        for (int i = 0; i < (TBF*HD)/256; ++i) {
            const int idx = threadIdx.x + i*256;
            drow[idx] = a*drow[idx] + brow[idx & 127];
        }
    }

    if (blockIdx.x == 0 && threadIdx.x < OUTD) {  // fused final head
        const int i = threadIdx.x;
        float seT = 0.f;
        #pragma unroll
        for (int rr = 0; rr < NREP; ++rr) seT += sumexp[rr];
        const float inv = 1.0f / seT;
        const float* wr = Wo + (size_t)i*OUTD;
        float acc = bo[i];
        #pragma unroll 8
        for (int jj = 0; jj < OUTD; ++jj) {
            float wv = wsum[jj] + wsum[64+jj] + wsum[128+jj] + wsum[192+jj];
            acc += (wv*inv) * wr[jj];
        }
        d_out[i] = acc;
        if (i == 0) {
            float tT = 0.f;
            #pragma unroll
            for (int rr = 0; rr < NREP; ++rr) tT += tsum[rr];
            d_out[OUTD] = tT * (1.0f/NCELLS);
        }
    }
}

extern "C" void kernel_launch(void* const* d_in, const int* in_sizes, int n_in,
                              void* d_out, int out_size, void* d_ws, size_t ws_size,
                              hipStream_t stream)
{
    const float* x   = (const float*)d_in[0];
    const float* hid = (const float*)d_in[1];
    const float* W1a = (const float*)d_in[2];
    const float* b1a = (const float*)d_in[3];
    const float* W2a = (const float*)d_in[4];
    const float* b2a = (const float*)d_in[5];
    const float* W1g = (const float*)d_in[6];
    const float* b1g = (const float*)d_in[7];
    const float* W2g = (const float*)d_in[8];
    const float* b2g = (const float*)d_in[9];
    const float* Wih = (const float*)d_in[10];
    const float* Whh = (const float*)d_in[11];
    const float* bih = (const float*)d_in[12];
    const float* bhh = (const float*)d_in[13];
    const float* Wo  = (const float*)d_in[14];
    const float* bo  = (const float*)d_in[15];
    const int*  step = (const int*)d_in[16];

    float* out  = (float*)d_out;
    float* newh_out = out + (OUTD + 1);

    unsigned short* wsu = (unsigned short*)d_ws;
    float* wsf = (float*)(wsu + WS_U_TOTAL);
    float* fsum   = wsf + WF_FSUM;
    float* wsum   = wsf + WF_WSUM;
    float* sumexp = wsf + WF_SE;
    float* tsum   = wsf + WF_TS;

    const size_t need = (size_t)WS_NH_OFF + (size_t)NT*sizeof(unsigned short);
    const int mode = (ws_size >= need) ? 1 : 0;
    unsigned short* nh16 = (unsigned short*)((char*)d_ws + WS_NH_OFF);

    hipMemsetAsync(fsum, 0, (NREP*NF*HD + NREP*OUTD + 2*NREP)*sizeof(float), stream);

    convert_kernel<<<(123584 + 255)/256, 256, 0, stream>>>(
        x, W1a, b1a, W2a, b2a, W1g, b1g, W2g, b2g, Wih, Whh, wsu, wsf);

    fused_cell_kernel<<<NBLK, NTH, 0, stream>>>(
        hid, bih, bhh, wsu, wsf, nh16, newh_out, fsum, wsum, sumexp, tsum, mode);

    faction_kernel<<<NCELLS/TBF, 256, 0, stream>>>(
        nh16, newh_out, fsum, step, Wo, bo, wsum, sumexp, tsum, out, mode);
}

// Round 7
// 225.033 us; speedup vs baseline: 1.4624x; 1.4624x over previous
//
#include <hip/hip_runtime.h>
#include <math.h>

// Problem constants
#define NCELLS 131072
#define IND 64
#define HD 128
#define OUTD 64
#define NF 8
#define FS 16384
#define DC 4096
#define TB 64             // cells per fused block
#define NBLK (NCELLS/TB)  // 2048
#define NTH 512
#define NREP 4            // atomic replication factor
#define NT (NCELLS*HD)

typedef __bf16 bf16x8 __attribute__((ext_vector_type(8)));
typedef float f32x4 __attribute__((ext_vector_type(4)));
typedef unsigned short us8 __attribute__((ext_vector_type(8)));

#define MFMA(a,b,c) __builtin_amdgcn_mfma_f32_16x16x32_bf16(a,b,c,0,0,0)

// ---- workspace layout ----
// Weights FRAGMENT-SWIZZLED (r2): fragment = contiguous 1KB; wave loads one
// fragment with a single coalesced dwordx4 at base + frag*512 + lane*8.
#define WS_W1H 0          // [256][128]  (KT=4, 64 frags)
#define WS_W2F 32768      // [64][256]   (KT=8, 32 frags)
#define WS_WIH 49152      // [384][64]   (KT=2, 48 frags)
#define WS_WHH 73728      // [384][128]  (KT=4, 96 frags)
#define WS_U_TOTAL 122880
// float region at (float*)((ushort*)ws + WS_U_TOTAL):
#define WF_B1   0         // [256] = b1 + x @ W1x.T
#define WF_B2   256       // [64]
#define WF_WT   320       // [384] = Wih[:,64] fp32
#define WF_FSUM 704       // [NREP][8][128]
#define WF_WSUM 4800      // [NREP][64]
#define WF_SE   5056
#define WF_TS   5060
#define WF_TOTAL 5064
#define WS_NH_OFF 266240  // align256; newh scratch (fp16)

// ---- LDS layout (ushort units), total 25600 us = 51200 B -> 3 blocks/CU ----
// Strides 136/264: rows are 16B-aligned (r6 lesson: odd strides misalign
// ds_read_b128 -> 2x whole-kernel penalty; bank conflicts are the lesser evil).
#define L_SC    0         // [64][136] us : h bf16
#define L_SH1   8704      // [64][264] us : relu(h1) bf16
#define L_SOF_F 4352      // float idx (us 8704): [64][68] f32 out (overlays sh1)
#define L_SOB   17408     // [64][72] us : out bf16
#define L_ST_F  11008     // [64] f32 t
#define L_SE_F  11072     // [64] f32 e^t
#define L_WSCR_F 11136    // [512] f32 reduction scratch
#define L_TOT   25600

__device__ __forceinline__ unsigned short f2bf(float f) {
    unsigned u = __builtin_bit_cast(unsigned, f);
    return (unsigned short)((u + 0x7FFFu + ((u >> 16) & 1u)) >> 16);
}
__device__ __forceinline__ float bf2f(unsigned short h) {
    return __builtin_bit_cast(float, (unsigned)h << 16);
}
__device__ __forceinline__ bf16x8 ld8(const unsigned short* p) {
    return __builtin_bit_cast(bf16x8, *(const us8*)p);
}
__device__ __forceinline__ float sigm(float v) {
    return __builtin_amdgcn_rcpf(1.f + __builtin_amdgcn_exp2f(-1.44269504f * v));
}
__device__ __forceinline__ float tanh_fast(float v) {
    return 1.f - 2.f * __builtin_amdgcn_rcpf(1.f + __builtin_amdgcn_exp2f(2.88539008f * v));
}

// ---- per-launch weight conversion fp32 -> bf16 fragment-swizzled ----
__global__ __launch_bounds__(256) void convert_kernel(
    const float* __restrict__ x,
    const float* __restrict__ W1a, const float* __restrict__ b1a,
    const float* __restrict__ W2a, const float* __restrict__ b2a,
    const float* __restrict__ W1g, const float* __restrict__ b1g,
    const float* __restrict__ W2g, const float* __restrict__ b2g,
    const float* __restrict__ Wih, const float* __restrict__ Whh,
    unsigned short* __restrict__ wsu, float* __restrict__ wsf)
{
    int i = blockIdx.x * 256 + threadIdx.x;
    if (i < 32768) {                         // W1H, KT=4
        int frag = i >> 9, r = i & 511;
        int lane = r >> 3, e = r & 7;
        int col = (frag >> 2)*16 + (lane & 15);
        int k   = (frag & 3)*32 + (lane >> 4)*8 + e;
        float v = (col < 128) ? W1a[col*192 + 64 + k] : W1g[(col-128)*192 + 64 + k];
        wsu[WS_W1H + i] = f2bf(v); return;
    }
    int j = i - 32768;
    if (j < 16384) {                         // W2F, KT=8
        int frag = j >> 9, r = j & 511;
        int lane = r >> 3, e = r & 7;
        int col = (frag >> 3)*16 + (lane & 15);
        int k   = (frag & 7)*32 + (lane >> 4)*8 + e;
        float v = (k < 128) ? W2a[col*128 + k] : -W2g[col*128 + (k-128)];
        wsu[WS_W2F + j] = f2bf(v); return;
    }
    j -= 16384;
    if (j < 24576) {                         // WIH (out-cols), KT=2
        int frag = j >> 9, r = j & 511;
        int lane = r >> 3, e = r & 7;
        int col = (frag >> 1)*16 + (lane & 15);
        int k   = (frag & 1)*32 + (lane >> 4)*8 + e;
        wsu[WS_WIH + j] = f2bf(Wih[col*65 + k]); return;
    }
    j -= 24576;
    if (j < 49152) {                         // WHH, KT=4
        int frag = j >> 9, r = j & 511;
        int lane = r >> 3, e = r & 7;
        int col = (frag >> 2)*16 + (lane & 15);
        int k   = (frag & 3)*32 + (lane >> 4)*8 + e;
        wsu[WS_WHH + j] = f2bf(Whh[col*128 + k]); return;
    }
    j -= 49152;
    if (j < 256) {                           // b1' = b1 + x @ W1x.T  (fp32)
        const float* wr = (j < 128) ? (W1a + j*192) : (W1g + (size_t)(j-128)*192);
        float base = (j < 128) ? b1a[j] : b1g[j-128];
        float dot = 0.f;
        #pragma unroll 8
        for (int k = 0; k < 64; ++k) dot += x[k] * wr[k];
        wsf[WF_B1 + j] = base + dot; return;
    }
    j -= 256;
    if (j < 64)  { wsf[WF_B2 + j] = b2a[j] - b2g[j]; return; }
    j -= 64;
    if (j < 384) { wsf[WF_WT + j] = Wih[j*65 + 64]; return; }
}

// ---- fused per-cell pipeline, TB=64, 8 waves (r5 structure verbatim) ----
// launch_bounds (512,4): VGPR cap 128. Tighter caps spill (r2: WRITE 67->424MB).
__global__ __launch_bounds__(NTH, 4) void fused_cell_kernel(
    const float* __restrict__ hiddens,
    const float* __restrict__ bih, const float* __restrict__ bhh,
    const unsigned short* __restrict__ wsu, const float* __restrict__ wsf,
    unsigned short* __restrict__ nh16, float* __restrict__ nhf,
    float* __restrict__ fsum, float* __restrict__ wsum,
    float* __restrict__ sumexp, float* __restrict__ tsum, int mode)
{
    __shared__ __align__(16) unsigned short sm[L_TOT];
    float* smf = (float*)sm;

    const int tid = threadIdx.x;
    const int cell0 = blockIdx.x * TB;
    const int w = tid >> 6, lane = tid & 63;
    const int q = lane >> 4, cL = lane & 15;
    const int rep = blockIdx.x & (NREP-1);

    // ---- prefetch GEMM1 B frags (compiler may sink; r5 measured 91.5 so-be-it) ----
    bf16x8 pB1[8];
    {
        const unsigned short* wp = wsu + WS_W1H + (w*2)*4*512 + lane*8;
        #pragma unroll
        for (int k = 0; k < 8; ++k) pB1[k] = ld8(wp + k*512);
    }

    // ---- phase 0: stage h bf16 into sc [64][136] ----
    for (int idx = tid; idx < TB*(HD/4); idx += NTH) {
        int c = idx >> 5, k4 = idx & 31;
        float4 v = ((const float4*)hiddens)[(size_t)(cell0+c)*(HD/4) + k4];
        unsigned p0 = (unsigned)f2bf(v.x) | ((unsigned)f2bf(v.y) << 16);
        unsigned p1 = (unsigned)f2bf(v.z) | ((unsigned)f2bf(v.w) << 16);
        *(unsigned*)&sm[L_SC + c*136 + k4*4]     = p0;
        *(unsigned*)&sm[L_SC + c*136 + k4*4 + 2] = p1;
    }
    __syncthreads();

    // ---- phase 1: GEMM1 (prefetch GEMM2 B at top) ----
    bf16x8 pB2[8];
    {
        const unsigned short* wp = wsu + WS_W2F + (w & 3)*8*512 + lane*8;
        #pragma unroll
        for (int k = 0; k < 8; ++k) pB2[k] = ld8(wp + k*512);
    }
    #pragma unroll
    for (int ct = 0; ct < 2; ++ct) {
        const int col = w*32 + ct*16 + cL;
        const float bias = wsf[WF_B1 + col];
        f32x4 acc[4];
        #pragma unroll
        for (int m = 0; m < 4; ++m) acc[m] = (f32x4){bias,bias,bias,bias};
        #pragma unroll
        for (int k = 0; k < 4; ++k) {
            bf16x8 B = pB1[ct*4 + k];
            #pragma unroll
            for (int m = 0; m < 4; ++m) {
                bf16x8 A = ld8(&sm[L_SC + (m*16+cL)*136 + k*32 + q*8]);
                acc[m] = MFMA(A, B, acc[m]);
            }
        }
        #pragma unroll
        for (int m = 0; m < 4; ++m)
            #pragma unroll
            for (int r = 0; r < 4; ++r)
                sm[L_SH1 + (m*16+q*4+r)*264 + col] = f2bf(fmaxf(acc[m][r], 0.f));
    }
    __syncthreads();

    // ---- phase 2: GEMM2 (prefetch GRU gi B at top) ----
    bf16x8 pGi[6];
    {
        const unsigned short* wiB = wsu + WS_WIH + lane*8;
        #pragma unroll
        for (int k = 0; k < 2; ++k) {
            pGi[k]   = ld8(wiB + ((     w)*2 + k)*512);
            pGi[2+k] = ld8(wiB + (( 8 + w)*2 + k)*512);
            pGi[4+k] = ld8(wiB + ((16 + w)*2 + k)*512);
        }
    }
    f32x4 o0, o1;
    {
        const int Mt0 = (w >> 2)*2, Mt1 = Mt0 + 1;
        const float bias = wsf[WF_B2 + (w & 3)*16 + cL];
        o0 = (f32x4){bias,bias,bias,bias}; o1 = o0;
        #pragma unroll
        for (int k = 0; k < 8; ++k) {
            bf16x8 B  = pB2[k];
            bf16x8 A0 = ld8(&sm[L_SH1 + (Mt0*16+cL)*264 + k*32 + q*8]);
            o0 = MFMA(A0, B, o0);
            bf16x8 A1 = ld8(&sm[L_SH1 + (Mt1*16+cL)*264 + k*32 + q*8]);
            o1 = MFMA(A1, B, o1);
        }
    }
    __syncthreads();   // all sh1 reads done; overlay region now writable

    // ---- phase 2b: out tiles into overlay (sof fp32, sob bf16) ----
    {
        const int col = (w & 3)*16 + cL;
        const int Mt0 = (w >> 2)*2, Mt1 = Mt0 + 1;
        #pragma unroll
        for (int r = 0; r < 4; ++r) {
            int r0 = Mt0*16 + q*4 + r, r1 = Mt1*16 + q*4 + r;
            smf[L_SOF_F + r0*68 + col] = o0[r];
            sm [L_SOB   + r0*72 + col] = f2bf(o0[r]);
            smf[L_SOF_F + r1*68 + col] = o1[r];
            sm [L_SOB   + r1*72 + col] = f2bf(o1[r]);
        }
    }
    __syncthreads();

    // ---- phase 3: t = mean(out^2), e^t ----
    {
        const int c = tid >> 3, g = tid & 7;
        f32x4 a = *(const f32x4*)&smf[L_SOF_F + c*68 + g*8];
        f32x4 b = *(const f32x4*)&smf[L_SOF_F + c*68 + g*8 + 4];
        float s = a[0]*a[0] + a[1]*a[1] + a[2]*a[2] + a[3]*a[3]
                + b[0]*b[0] + b[1]*b[1] + b[2]*b[2] + b[3]*b[3];
        s += __shfl_xor(s, 1);
        s += __shfl_xor(s, 2);
        s += __shfl_xor(s, 4);
        if (g == 0) {
            float t = s * (1.0f/OUTD);
            smf[L_ST_F + c] = t;
            smf[L_SE_F + c] = __builtin_amdgcn_exp2f(t * 1.44269504f);
        }
    }
    __syncthreads();

    // ---- phase 4: GRU gates, merged 4-M-tile pass ----
    const int fidx = (int)(blockIdx.x >> 8);
    {
        const int j = w*16 + cL;
        const float bR = bih[j]      + bhh[j];
        const float bZ = bih[HD+j]   + bhh[HD+j];
        const float bI = bih[2*HD+j];
        const float bH = bhh[2*HD+j];
        const float wtR = wsf[WF_WT + j];
        const float wtZ = wsf[WF_WT + HD + j];
        const float wtI = wsf[WF_WT + 2*HD + j];
        f32x4 R[4], Z[4], I[4], H[4];
        #pragma unroll
        for (int m = 0; m < 4; ++m) {
            R[m] = (f32x4){bR,bR,bR,bR}; Z[m] = (f32x4){bZ,bZ,bZ,bZ};
            I[m] = (f32x4){bI,bI,bI,bI}; H[m] = (f32x4){bH,bH,bH,bH};
        }
        #pragma unroll
        for (int k = 0; k < 2; ++k) {        // gi: K=64
            bf16x8 Br = pGi[k], Bz = pGi[2+k], Bi = pGi[4+k];
            #pragma unroll
            for (int m = 0; m < 4; ++m) {
                bf16x8 A = ld8(&sm[L_SOB + (m*16+cL)*72 + k*32 + q*8]);
                R[m] = MFMA(A, Br, R[m]);
                Z[m] = MFMA(A, Bz, Z[m]);
                I[m] = MFMA(A, Bi, I[m]);
            }
        }
        const unsigned short* whB = wsu + WS_WHH + lane*8;
        #pragma unroll
        for (int k = 0; k < 4; ++k) {        // gh: K=128
            bf16x8 Br = ld8(whB + ((     w)*4 + k)*512);
            bf16x8 Bz = ld8(whB + (( 8 + w)*4 + k)*512);
            bf16x8 Bn = ld8(whB + ((16 + w)*4 + k)*512);
            #pragma unroll
            for (int m = 0; m < 4; ++m) {
                bf16x8 A = ld8(&sm[L_SC + (m*16+cL)*136 + k*32 + q*8]);
                R[m] = MFMA(A, Br, R[m]);
                Z[m] = MFMA(A, Bz, Z[m]);
                H[m] = MFMA(A, Bn, H[m]);
            }
        }
        float colsum = 0.f;
        #pragma unroll
        for (int m = 0; m < 4; ++m) {
            #pragma unroll
            for (int r = 0; r < 4; ++r) {
                const int row = m*16 + q*4 + r;
                const float tv = smf[L_ST_F + row];
                const float rr = sigm(R[m][r] + tv*wtR);
                const float zz = sigm(Z[m][r] + tv*wtZ);
                const float nn = tanh_fast(I[m][r] + tv*wtI + rr*H[m][r]);
                const float hold = bf2f(sm[L_SC + row*136 + j]);
                const float hv = (1.f - zz)*nn + zz*hold;
                const size_t g = (size_t)(cell0+row)*HD + j;
                if (mode) nh16[g] = __builtin_bit_cast(unsigned short, (_Float16)hv);
                else      nhf[g]  = hv;
                colsum += hv;
            }
        }
        colsum += __shfl_xor(colsum, 16);
        colsum += __shfl_xor(colsum, 32);
        if (q == 0) unsafeAtomicAdd(&fsum[(rep*NF + fidx)*HD + j], colsum);
    }

    // ---- phase 5: softmax-weighted sums ----
    {
        const int col = tid & 63, cg = tid >> 6;
        float wacc = 0.f;
        #pragma unroll
        for (int c8 = 0; c8 < 8; ++c8) {
            const int c = cg*8 + c8;
            wacc += smf[L_SE_F + c] * smf[L_SOF_F + c*68 + col];
        }
        smf[L_WSCR_F + cg*64 + col] = wacc;
    }
    __syncthreads();
    if (tid < 64) {
        float wacc = 0.f;
        #pragma unroll
        for (int g = 0; g < 8; ++g) wacc += smf[L_WSCR_F + g*64 + tid];
        unsafeAtomicAdd(&wsum[rep*64 + tid], wacc);
        float e = smf[L_SE_F + tid];
        float t = smf[L_ST_F + tid];
        #pragma unroll
        for (int d = 1; d < 64; d <<= 1) { e += __shfl_xor(e, d); t += __shfl_xor(t, d); }
        if (tid == 0) { unsafeAtomicAdd(&sumexp[rep], e); unsafeAtomicAdd(&tsum[rep], t); }
    }
}

// ---- faction sync: dst = a*h + b[j]; fp16 scratch read (half traffic) ----
#define TBF 64
__global__ __launch_bounds__(256) void faction_kernel(
    const unsigned short* __restrict__ src16, float* __restrict__ dst,
    const float* __restrict__ fsum, const int* __restrict__ step,
    const float* __restrict__ Wo, const float* __restrict__ bo,
    const float* __restrict__ wsum, const float* __restrict__ sumexp,
    const float* __restrict__ tsum, float* __restrict__ d_out, int mode)
{
    __shared__ float bnon[HD], bdeb[HD];
    const int cell0 = blockIdx.x * TBF;
    const int f = blockIdx.x >> 8;            // 256 blocks per faction
    if (threadIdx.x < HD) {
        const int jc = threadIdx.x;
        float s = 0.f, fm_s = 0.f;
        #pragma unroll
        for (int rr = 0; rr < NREP; ++rr) {
            #pragma unroll
            for (int ff = 0; ff < NF; ++ff) s += fsum[(rr*NF+ff)*HD + jc];
            fm_s += fsum[(rr*NF+f)*HD + jc];
        }
        const float go = s * (1.0f/NCELLS);
        const float fm = fm_s * (1.0f/FS);
        bnon[jc] = 0.15f*fm;
        bdeb[jc] = 0.1275f*fm + 0.15f*go;
    }
    __syncthreads();
    const bool debate = (step[0] > 5) && ((cell0 & (FS-1)) < DC);  // uniform per block
    const float a = debate ? 0.7225f : 0.85f;
    const float* brow = debate ? bdeb : bnon;
    float* drow = dst + (size_t)cell0*HD;
    if (mode) {
        const unsigned short* srow = src16 + (size_t)cell0*HD;
        #pragma unroll
        for (int it = 0; it < 4; ++it) {
            const int e0 = (threadIdx.x + it*256) * 8;   // 16B-aligned, cell-local
            us8 v = *(const us8*)(srow + e0);
            const int jb = e0 & 127;
            #pragma unroll
            for (int u = 0; u < 8; ++u) {
                float hv = (float)__builtin_bit_cast(_Float16, (unsigned short)v[u]);
                drow[e0 + u] = a*hv + brow[jb + u];
            }
        }
    } else {                                   // fallback: fp32 in-place
        #pragma unroll
        for (int i = 0; i < (TBF*HD)/256; ++i) {
            const int idx = threadIdx.x + i*256;
            drow[idx] = a*drow[idx] + brow[idx & 127];
        }
    }

    if (blockIdx.x == 0 && threadIdx.x < OUTD) {  // fused final head
        const int i = threadIdx.x;
        float seT = 0.f;
        #pragma unroll
        for (int rr = 0; rr < NREP; ++rr) seT += sumexp[rr];
        const float inv = 1.0f / seT;
        const float* wr = Wo + (size_t)i*OUTD;
        float acc = bo[i];
        #pragma unroll 8
        for (int jj = 0; jj < OUTD; ++jj) {
            float wv = wsum[jj] + wsum[64+jj] + wsum[128+jj] + wsum[192+jj];
            acc += (wv*inv) * wr[jj];
        }
        d_out[i] = acc;
        if (i == 0) {
            float tT = 0.f;
            #pragma unroll
            for (int rr = 0; rr < NREP; ++rr) tT += tsum[rr];
            d_out[OUTD] = tT * (1.0f/NCELLS);
        }
    }
}

extern "C" void kernel_launch(void* const* d_in, const int* in_sizes, int n_in,
                              void* d_out, int out_size, void* d_ws, size_t ws_size,
                              hipStream_t stream)
{
    const float* x   = (const float*)d_in[0];
    const float* hid = (const float*)d_in[1];
    const float* W1a = (const float*)d_in[2];
    const float* b1a = (const float*)d_in[3];
    const float* W2a = (const float*)d_in[4];
    const float* b2a = (const float*)d_in[5];
    const float* W1g = (const float*)d_in[6];
    const float* b1g = (const float*)d_in[7];
    const float* W2g = (const float*)d_in[8];
    const float* b2g = (const float*)d_in[9];
    const float* Wih = (const float*)d_in[10];
    const float* Whh = (const float*)d_in[11];
    const float* bih = (const float*)d_in[12];
    const float* bhh = (const float*)d_in[13];
    const float* Wo  = (const float*)d_in[14];
    const float* bo  = (const float*)d_in[15];
    const int*  step = (const int*)d_in[16];

    float* out  = (float*)d_out;
    float* newh_out = out + (OUTD + 1);

    unsigned short* wsu = (unsigned short*)d_ws;
    float* wsf = (float*)(wsu + WS_U_TOTAL);
    float* fsum   = wsf + WF_FSUM;
    float* wsum   = wsf + WF_WSUM;
    float* sumexp = wsf + WF_SE;
    float* tsum   = wsf + WF_TS;

    const size_t need = (size_t)WS_NH_OFF + (size_t)NT*sizeof(unsigned short);
    const int mode = (ws_size >= need) ? 1 : 0;
    unsigned short* nh16 = (unsigned short*)((char*)d_ws + WS_NH_OFF);

    hipMemsetAsync(fsum, 0, (NREP*NF*HD + NREP*OUTD + 2*NREP)*sizeof(float), stream);

    convert_kernel<<<(123584 + 255)/256, 256, 0, stream>>>(
        x, W1a, b1a, W2a, b2a, W1g, b1g, W2g, b2g, Wih, Whh, wsu, wsf);

    fused_cell_kernel<<<NBLK, NTH, 0, stream>>>(
        hid, bih, bhh, wsu, wsf, nh16, newh_out, fsum, wsum, sumexp, tsum, mode);

    faction_kernel<<<NCELLS/TBF, 256, 0, stream>>>(
        nh16, newh_out, fsum, step, Wo, bo, wsum, sumexp, tsum, out, mode);
}

// Round 8
// 219.355 us; speedup vs baseline: 1.5002x; 1.0259x over previous
//
#include <hip/hip_runtime.h>
#include <math.h>

// Problem constants
#define NCELLS 131072
#define IND 64
#define HD 128
#define OUTD 64
#define NF 8
#define FS 16384
#define DC 4096
#define TB 64             // cells per fused block
#define NBLK (NCELLS/TB)  // 2048
#define NTH 512
#define NREP 4            // atomic replication factor
#define NT (NCELLS*HD)

typedef __bf16 bf16x8 __attribute__((ext_vector_type(8)));
typedef float f32x4 __attribute__((ext_vector_type(4)));
typedef unsigned short us8 __attribute__((ext_vector_type(8)));

#define MFMA(a,b,c) __builtin_amdgcn_mfma_f32_16x16x32_bf16(a,b,c,0,0,0)

// ---- workspace layout ----
// Weights FRAGMENT-SWIZZLED (r2): fragment = contiguous 1KB; wave loads one
// fragment with a single coalesced dwordx4 at base + frag*512 + lane*8.
#define WS_W1H 0          // [256][128]  (KT=4, 64 frags)
#define WS_W2F 32768      // [64][256]   (KT=8, 32 frags)
#define WS_WIH 49152      // [384][64]   (KT=2, 48 frags)
#define WS_WHH 73728      // [384][128]  (KT=4, 96 frags)
#define WS_U_TOTAL 122880
// float region at (float*)((ushort*)ws + WS_U_TOTAL):
#define WF_B1   0         // [256] = b1 + x @ W1x.T
#define WF_B2   256       // [64]
#define WF_WT   320       // [384] = Wih[:,64] fp32
#define WF_FSUM 704       // [NREP][8][128]
#define WF_WSUM 4800      // [NREP][64]
#define WF_SE   5056
#define WF_TS   5060
#define WF_TOTAL 5064
#define WS_NH_OFF 266240  // align256; newh scratch (fp16)

// ---- LDS layout (ushort units), total 25600 us = 51200 B -> 3 blocks/CU ----
// Strides 136/264: rows are 16B-aligned (r6 lesson: odd strides misalign
// ds_read_b128 -> 2x whole-kernel penalty; bank conflicts are the lesser evil).
#define L_SC    0         // [64][136] us : h bf16
#define L_SH1   8704      // [64][264] us : relu(h1) bf16
#define L_SOF_F 4352      // float idx (us 8704): [64][68] f32 out (overlays sh1)
#define L_SOB   17408     // [64][72] us : out bf16
#define L_ST_F  11008     // [64] f32 t
#define L_SE_F  11072     // [64] f32 e^t
#define L_WSCR_F 11136    // [512] f32 reduction scratch
#define L_TOT   25600

__device__ __forceinline__ unsigned short f2bf(float f) {
    unsigned u = __builtin_bit_cast(unsigned, f);
    return (unsigned short)((u + 0x7FFFu + ((u >> 16) & 1u)) >> 16);
}
__device__ __forceinline__ float bf2f(unsigned short h) {
    return __builtin_bit_cast(float, (unsigned)h << 16);
}
__device__ __forceinline__ bf16x8 ld8(const unsigned short* p) {
    return __builtin_bit_cast(bf16x8, *(const us8*)p);
}
__device__ __forceinline__ float sigm(float v) {
    return __builtin_amdgcn_rcpf(1.f + __builtin_amdgcn_exp2f(-1.44269504f * v));
}
__device__ __forceinline__ float tanh_fast(float v) {
    return 1.f - 2.f * __builtin_amdgcn_rcpf(1.f + __builtin_amdgcn_exp2f(2.88539008f * v));
}

// ---- per-launch weight conversion fp32 -> bf16 fragment-swizzled ----
__global__ __launch_bounds__(256) void convert_kernel(
    const float* __restrict__ x,
    const float* __restrict__ W1a, const float* __restrict__ b1a,
    const float* __restrict__ W2a, const float* __restrict__ b2a,
    const float* __restrict__ W1g, const float* __restrict__ b1g,
    const float* __restrict__ W2g, const float* __restrict__ b2g,
    const float* __restrict__ Wih, const float* __restrict__ Whh,
    unsigned short* __restrict__ wsu, float* __restrict__ wsf)
{
    int i = blockIdx.x * 256 + threadIdx.x;
    if (i < 32768) {                         // W1H, KT=4
        int frag = i >> 9, r = i & 511;
        int lane = r >> 3, e = r & 7;
        int col = (frag >> 2)*16 + (lane & 15);
        int k   = (frag & 3)*32 + (lane >> 4)*8 + e;
        float v = (col < 128) ? W1a[col*192 + 64 + k] : W1g[(col-128)*192 + 64 + k];
        wsu[WS_W1H + i] = f2bf(v); return;
    }
    int j = i - 32768;
    if (j < 16384) {                         // W2F, KT=8
        int frag = j >> 9, r = j & 511;
        int lane = r >> 3, e = r & 7;
        int col = (frag >> 3)*16 + (lane & 15);
        int k   = (frag & 7)*32 + (lane >> 4)*8 + e;
        float v = (k < 128) ? W2a[col*128 + k] : -W2g[col*128 + (k-128)];
        wsu[WS_W2F + j] = f2bf(v); return;
    }
    j -= 16384;
    if (j < 24576) {                         // WIH (out-cols), KT=2
        int frag = j >> 9, r = j & 511;
        int lane = r >> 3, e = r & 7;
        int col = (frag >> 1)*16 + (lane & 15);
        int k   = (frag & 1)*32 + (lane >> 4)*8 + e;
        wsu[WS_WIH + j] = f2bf(Wih[col*65 + k]); return;
    }
    j -= 24576;
    if (j < 49152) {                         // WHH, KT=4
        int frag = j >> 9, r = j & 511;
        int lane = r >> 3, e = r & 7;
        int col = (frag >> 2)*16 + (lane & 15);
        int k   = (frag & 3)*32 + (lane >> 4)*8 + e;
        wsu[WS_WHH + j] = f2bf(Whh[col*128 + k]); return;
    }
    j -= 49152;
    if (j < 256) {                           // b1' = b1 + x @ W1x.T  (fp32)
        const float* wr = (j < 128) ? (W1a + j*192) : (W1g + (size_t)(j-128)*192);
        float base = (j < 128) ? b1a[j] : b1g[j-128];
        float dot = 0.f;
        #pragma unroll 8
        for (int k = 0; k < 64; ++k) dot += x[k] * wr[k];
        wsf[WF_B1 + j] = base + dot; return;
    }
    j -= 256;
    if (j < 64)  { wsf[WF_B2 + j] = b2a[j] - b2g[j]; return; }
    j -= 64;
    if (j < 384) { wsf[WF_WT + j] = Wih[j*65 + 64]; return; }
}

// ---- fused per-cell pipeline, TB=64, 8 waves (r7 verbatim) ----
// launch_bounds (512,4): VGPR cap 128. Tighter caps spill (r2: WRITE 67->424MB).
__global__ __launch_bounds__(NTH, 4) void fused_cell_kernel(
    const float* __restrict__ hiddens,
    const float* __restrict__ bih, const float* __restrict__ bhh,
    const unsigned short* __restrict__ wsu, const float* __restrict__ wsf,
    unsigned short* __restrict__ nh16, float* __restrict__ nhf,
    float* __restrict__ fsum, float* __restrict__ wsum,
    float* __restrict__ sumexp, float* __restrict__ tsum, int mode)
{
    __shared__ __align__(16) unsigned short sm[L_TOT];
    float* smf = (float*)sm;

    const int tid = threadIdx.x;
    const int cell0 = blockIdx.x * TB;
    const int w = tid >> 6, lane = tid & 63;
    const int q = lane >> 4, cL = lane & 15;
    const int rep = blockIdx.x & (NREP-1);

    // ---- prefetch GEMM1 B frags ----
    bf16x8 pB1[8];
    {
        const unsigned short* wp = wsu + WS_W1H + (w*2)*4*512 + lane*8;
        #pragma unroll
        for (int k = 0; k < 8; ++k) pB1[k] = ld8(wp + k*512);
    }

    // ---- phase 0: stage h bf16 into sc [64][136] ----
    for (int idx = tid; idx < TB*(HD/4); idx += NTH) {
        int c = idx >> 5, k4 = idx & 31;
        float4 v = ((const float4*)hiddens)[(size_t)(cell0+c)*(HD/4) + k4];
        unsigned p0 = (unsigned)f2bf(v.x) | ((unsigned)f2bf(v.y) << 16);
        unsigned p1 = (unsigned)f2bf(v.z) | ((unsigned)f2bf(v.w) << 16);
        *(unsigned*)&sm[L_SC + c*136 + k4*4]     = p0;
        *(unsigned*)&sm[L_SC + c*136 + k4*4 + 2] = p1;
    }
    __syncthreads();

    // ---- phase 1: GEMM1 (prefetch GEMM2 B at top) ----
    bf16x8 pB2[8];
    {
        const unsigned short* wp = wsu + WS_W2F + (w & 3)*8*512 + lane*8;
        #pragma unroll
        for (int k = 0; k < 8; ++k) pB2[k] = ld8(wp + k*512);
    }
    #pragma unroll
    for (int ct = 0; ct < 2; ++ct) {
        const int col = w*32 + ct*16 + cL;
        const float bias = wsf[WF_B1 + col];
        f32x4 acc[4];
        #pragma unroll
        for (int m = 0; m < 4; ++m) acc[m] = (f32x4){bias,bias,bias,bias};
        #pragma unroll
        for (int k = 0; k < 4; ++k) {
            bf16x8 B = pB1[ct*4 + k];
            #pragma unroll
            for (int m = 0; m < 4; ++m) {
                bf16x8 A = ld8(&sm[L_SC + (m*16+cL)*136 + k*32 + q*8]);
                acc[m] = MFMA(A, B, acc[m]);
            }
        }
        #pragma unroll
        for (int m = 0; m < 4; ++m)
            #pragma unroll
            for (int r = 0; r < 4; ++r)
                sm[L_SH1 + (m*16+q*4+r)*264 + col] = f2bf(fmaxf(acc[m][r], 0.f));
    }
    __syncthreads();

    // ---- phase 2: GEMM2 (prefetch GRU gi B at top) ----
    bf16x8 pGi[6];
    {
        const unsigned short* wiB = wsu + WS_WIH + lane*8;
        #pragma unroll
        for (int k = 0; k < 2; ++k) {
            pGi[k]   = ld8(wiB + ((     w)*2 + k)*512);
            pGi[2+k] = ld8(wiB + (( 8 + w)*2 + k)*512);
            pGi[4+k] = ld8(wiB + ((16 + w)*2 + k)*512);
        }
    }
    f32x4 o0, o1;
    {
        const int Mt0 = (w >> 2)*2, Mt1 = Mt0 + 1;
        const float bias = wsf[WF_B2 + (w & 3)*16 + cL];
        o0 = (f32x4){bias,bias,bias,bias}; o1 = o0;
        #pragma unroll
        for (int k = 0; k < 8; ++k) {
            bf16x8 B  = pB2[k];
            bf16x8 A0 = ld8(&sm[L_SH1 + (Mt0*16+cL)*264 + k*32 + q*8]);
            o0 = MFMA(A0, B, o0);
            bf16x8 A1 = ld8(&sm[L_SH1 + (Mt1*16+cL)*264 + k*32 + q*8]);
            o1 = MFMA(A1, B, o1);
        }
    }
    __syncthreads();   // all sh1 reads done; overlay region now writable

    // ---- phase 2b: out tiles into overlay (sof fp32, sob bf16) ----
    {
        const int col = (w & 3)*16 + cL;
        const int Mt0 = (w >> 2)*2, Mt1 = Mt0 + 1;
        #pragma unroll
        for (int r = 0; r < 4; ++r) {
            int r0 = Mt0*16 + q*4 + r, r1 = Mt1*16 + q*4 + r;
            smf[L_SOF_F + r0*68 + col] = o0[r];
            sm [L_SOB   + r0*72 + col] = f2bf(o0[r]);
            smf[L_SOF_F + r1*68 + col] = o1[r];
            sm [L_SOB   + r1*72 + col] = f2bf(o1[r]);
        }
    }
    __syncthreads();

    // ---- phase 3: t = mean(out^2), e^t ----
    {
        const int c = tid >> 3, g = tid & 7;
        f32x4 a = *(const f32x4*)&smf[L_SOF_F + c*68 + g*8];
        f32x4 b = *(const f32x4*)&smf[L_SOF_F + c*68 + g*8 + 4];
        float s = a[0]*a[0] + a[1]*a[1] + a[2]*a[2] + a[3]*a[3]
                + b[0]*b[0] + b[1]*b[1] + b[2]*b[2] + b[3]*b[3];
        s += __shfl_xor(s, 1);
        s += __shfl_xor(s, 2);
        s += __shfl_xor(s, 4);
        if (g == 0) {
            float t = s * (1.0f/OUTD);
            smf[L_ST_F + c] = t;
            smf[L_SE_F + c] = __builtin_amdgcn_exp2f(t * 1.44269504f);
        }
    }
    __syncthreads();

    // ---- phase 4: GRU gates, merged 4-M-tile pass ----
    const int fidx = (int)(blockIdx.x >> 8);
    {
        const int j = w*16 + cL;
        const float bR = bih[j]      + bhh[j];
        const float bZ = bih[HD+j]   + bhh[HD+j];
        const float bI = bih[2*HD+j];
        const float bH = bhh[2*HD+j];
        const float wtR = wsf[WF_WT + j];
        const float wtZ = wsf[WF_WT + HD + j];
        const float wtI = wsf[WF_WT + 2*HD + j];
        f32x4 R[4], Z[4], I[4], H[4];
        #pragma unroll
        for (int m = 0; m < 4; ++m) {
            R[m] = (f32x4){bR,bR,bR,bR}; Z[m] = (f32x4){bZ,bZ,bZ,bZ};
            I[m] = (f32x4){bI,bI,bI,bI}; H[m] = (f32x4){bH,bH,bH,bH};
        }
        #pragma unroll
        for (int k = 0; k < 2; ++k) {        // gi: K=64
            bf16x8 Br = pGi[k], Bz = pGi[2+k], Bi = pGi[4+k];
            #pragma unroll
            for (int m = 0; m < 4; ++m) {
                bf16x8 A = ld8(&sm[L_SOB + (m*16+cL)*72 + k*32 + q*8]);
                R[m] = MFMA(A, Br, R[m]);
                Z[m] = MFMA(A, Bz, Z[m]);
                I[m] = MFMA(A, Bi, I[m]);
            }
        }
        const unsigned short* whB = wsu + WS_WHH + lane*8;
        #pragma unroll
        for (int k = 0; k < 4; ++k) {        // gh: K=128
            bf16x8 Br = ld8(whB + ((     w)*4 + k)*512);
            bf16x8 Bz = ld8(whB + (( 8 + w)*4 + k)*512);
            bf16x8 Bn = ld8(whB + ((16 + w)*4 + k)*512);
            #pragma unroll
            for (int m = 0; m < 4; ++m) {
                bf16x8 A = ld8(&sm[L_SC + (m*16+cL)*136 + k*32 + q*8]);
                R[m] = MFMA(A, Br, R[m]);
                Z[m] = MFMA(A, Bz, Z[m]);
                H[m] = MFMA(A, Bn, H[m]);
            }
        }
        float colsum = 0.f;
        #pragma unroll
        for (int m = 0; m < 4; ++m) {
            #pragma unroll
            for (int r = 0; r < 4; ++r) {
                const int row = m*16 + q*4 + r;
                const float tv = smf[L_ST_F + row];
                const float rr = sigm(R[m][r] + tv*wtR);
                const float zz = sigm(Z[m][r] + tv*wtZ);
                const float nn = tanh_fast(I[m][r] + tv*wtI + rr*H[m][r]);
                const float hold = bf2f(sm[L_SC + row*136 + j]);
                const float hv = (1.f - zz)*nn + zz*hold;
                const size_t g = (size_t)(cell0+row)*HD + j;
                if (mode) nh16[g] = __builtin_bit_cast(unsigned short, (_Float16)hv);
                else      nhf[g]  = hv;
                colsum += hv;
            }
        }
        colsum += __shfl_xor(colsum, 16);
        colsum += __shfl_xor(colsum, 32);
        if (q == 0) unsafeAtomicAdd(&fsum[(rep*NF + fidx)*HD + j], colsum);
    }

    // ---- phase 5: softmax-weighted sums ----
    {
        const int col = tid & 63, cg = tid >> 6;
        float wacc = 0.f;
        #pragma unroll
        for (int c8 = 0; c8 < 8; ++c8) {
            const int c = cg*8 + c8;
            wacc += smf[L_SE_F + c] * smf[L_SOF_F + c*68 + col];
        }
        smf[L_WSCR_F + cg*64 + col] = wacc;
    }
    __syncthreads();
    if (tid < 64) {
        float wacc = 0.f;
        #pragma unroll
        for (int g = 0; g < 8; ++g) wacc += smf[L_WSCR_F + g*64 + tid];
        unsafeAtomicAdd(&wsum[rep*64 + tid], wacc);
        float e = smf[L_SE_F + tid];
        float t = smf[L_ST_F + tid];
        #pragma unroll
        for (int d = 1; d < 64; d <<= 1) { e += __shfl_xor(e, d); t += __shfl_xor(t, d); }
        if (tid == 0) { unsafeAtomicAdd(&sumexp[rep], e); unsafeAtomicAdd(&tsum[rep], t); }
    }
}

// ---- faction sync: dst = a*h + b[j] ----
// r8: mode path rewritten LANE-CONTIGUOUS (idx = tid + it*256). r7 had each
// thread own 8 consecutive elements -> store lanes strided 32B -> partial-line
// HBM writes (RMW ~8x amplification). Dense per-instruction coverage now:
// fp16 load = 512B/wave contiguous, fp32 store = 1024B/wave contiguous.
#define TBF 64
__global__ __launch_bounds__(256) void faction_kernel(
    const unsigned short* __restrict__ src16, float* __restrict__ dst,
    const float* __restrict__ fsum, const int* __restrict__ step,
    const float* __restrict__ Wo, const float* __restrict__ bo,
    const float* __restrict__ wsum, const float* __restrict__ sumexp,
    const float* __restrict__ tsum, float* __restrict__ d_out, int mode)
{
    __shared__ float bnon[HD], bdeb[HD];
    const int cell0 = blockIdx.x * TBF;
    const int f = blockIdx.x >> 8;            // 256 blocks per faction
    if (threadIdx.x < HD) {
        const int jc = threadIdx.x;
        float s = 0.f, fm_s = 0.f;
        #pragma unroll
        for (int rr = 0; rr < NREP; ++rr) {
            #pragma unroll
            for (int ff = 0; ff < NF; ++ff) s += fsum[(rr*NF+ff)*HD + jc];
            fm_s += fsum[(rr*NF+f)*HD + jc];
        }
        const float go = s * (1.0f/NCELLS);
        const float fm = fm_s * (1.0f/FS);
        bnon[jc] = 0.15f*fm;
        bdeb[jc] = 0.1275f*fm + 0.15f*go;
    }
    __syncthreads();
    const bool debate = (step[0] > 5) && ((cell0 & (FS-1)) < DC);  // uniform per block
    const float a = debate ? 0.7225f : 0.85f;
    const float* brow = debate ? bdeb : bnon;
    float* drow = dst + (size_t)cell0*HD;
    if (mode) {
        const unsigned short* srow = src16 + (size_t)cell0*HD;
        #pragma unroll
        for (int it = 0; it < (TBF*HD)/256; ++it) {   // 32 iters, lane-contiguous
            const int idx = threadIdx.x + it*256;
            float hv = (float)__builtin_bit_cast(_Float16, srow[idx]);
            drow[idx] = a*hv + brow[idx & 127];
        }
    } else {                                   // fallback: fp32 in-place
        #pragma unroll
        for (int i = 0; i < (TBF*HD)/256; ++i) {
            const int idx = threadIdx.x + i*256;
            drow[idx] = a*drow[idx] + brow[idx & 127];
        }
    }

    if (blockIdx.x == 0 && threadIdx.x < OUTD) {  // fused final head
        const int i = threadIdx.x;
        float seT = 0.f;
        #pragma unroll
        for (int rr = 0; rr < NREP; ++rr) seT += sumexp[rr];
        const float inv = 1.0f / seT;
        const float* wr = Wo + (size_t)i*OUTD;
        float acc = bo[i];
        #pragma unroll 8
        for (int jj = 0; jj < OUTD; ++jj) {
            float wv = wsum[jj] + wsum[64+jj] + wsum[128+jj] + wsum[192+jj];
            acc += (wv*inv) * wr[jj];
        }
        d_out[i] = acc;
        if (i == 0) {
            float tT = 0.f;
            #pragma unroll
            for (int rr = 0; rr < NREP; ++rr) tT += tsum[rr];
            d_out[OUTD] = tT * (1.0f/NCELLS);
        }
    }
}

extern "C" void kernel_launch(void* const* d_in, const int* in_sizes, int n_in,
                              void* d_out, int out_size, void* d_ws, size_t ws_size,
                              hipStream_t stream)
{
    const float* x   = (const float*)d_in[0];
    const float* hid = (const float*)d_in[1];
    const float* W1a = (const float*)d_in[2];
    const float* b1a = (const float*)d_in[3];
    const float* W2a = (const float*)d_in[4];
    const float* b2a = (const float*)d_in[5];
    const float* W1g = (const float*)d_in[6];
    const float* b1g = (const float*)d_in[7];
    const float* W2g = (const float*)d_in[8];
    const float* b2g = (const float*)d_in[9];
    const float* Wih = (const float*)d_in[10];
    const float* Whh = (const float*)d_in[11];
    const float* bih = (const float*)d_in[12];
    const float* bhh = (const float*)d_in[13];
    const float* Wo  = (const float*)d_in[14];
    const float* bo  = (const float*)d_in[15];
    const int*  step = (const int*)d_in[16];

    float* out  = (float*)d_out;
    float* newh_out = out + (OUTD + 1);

    unsigned short* wsu = (unsigned short*)d_ws;
    float* wsf = (float*)(wsu + WS_U_TOTAL);
    float* fsum   = wsf + WF_FSUM;
    float* wsum   = wsf + WF_WSUM;
    float* sumexp = wsf + WF_SE;
    float* tsum   = wsf + WF_TS;

    const size_t need = (size_t)WS_NH_OFF + (size_t)NT*sizeof(unsigned short);
    const int mode = (ws_size >= need) ? 1 : 0;
    unsigned short* nh16 = (unsigned short*)((char*)d_ws + WS_NH_OFF);

    hipMemsetAsync(fsum, 0, (NREP*NF*HD + NREP*OUTD + 2*NREP)*sizeof(float), stream);

    convert_kernel<<<(123584 + 255)/256, 256, 0, stream>>>(
        x, W1a, b1a, W2a, b2a, W1g, b1g, W2g, b2g, Wih, Whh, wsu, wsf);

    fused_cell_kernel<<<NBLK, NTH, 0, stream>>>(
        hid, bih, bhh, wsu, wsf, nh16, newh_out, fsum, wsum, sumexp, tsum, mode);

    faction_kernel<<<NCELLS/TBF, 256, 0, stream>>>(
        nh16, newh_out, fsum, step, Wo, bo, wsum, sumexp, tsum, out, mode);
}

// Round 9
// 219.187 us; speedup vs baseline: 1.5014x; 1.0008x over previous
//
#include <hip/hip_runtime.h>
#include <math.h>

// Problem constants
#define NCELLS 131072
#define IND 64
#define HD 128
#define OUTD 64
#define NF 8
#define FS 16384
#define DC 4096
#define TB 64             // cells per fused block
#define NBLK (NCELLS/TB)  // 2048
#define NTH 512
#define NREP 4            // atomic replication factor
#define NT (NCELLS*HD)

typedef __bf16 bf16x8 __attribute__((ext_vector_type(8)));
typedef float f32x4 __attribute__((ext_vector_type(4)));
typedef unsigned short us8 __attribute__((ext_vector_type(8)));

#define MFMA(a,b,c) __builtin_amdgcn_mfma_f32_16x16x32_bf16(a,b,c,0,0,0)

// ---- workspace layout ----
// Weights FRAGMENT-SWIZZLED (r2): fragment = contiguous 1KB; wave loads one
// fragment with a single coalesced dwordx4 at base + frag*512 + lane*8.
#define WS_W1H 0          // [256][128]  (KT=4, 64 frags)
#define WS_W2F 32768      // [64][256]   (KT=8, 32 frags)
#define WS_WIH 49152      // [384][64]   (KT=2, 48 frags)
#define WS_WHH 73728      // [384][128]  (KT=4, 96 frags)
#define WS_U_TOTAL 122880
// float region at (float*)((ushort*)ws + WS_U_TOTAL):
#define WF_B1   0         // [256] = b1 + x @ W1x.T
#define WF_B2   256       // [64]
#define WF_WT   320       // [384] = Wih[:,64] fp32
#define WF_FSUM 704       // [NREP][8][128]
#define WF_WSUM 4800      // [NREP][64]
#define WF_SE   5056
#define WF_TS   5060
#define WF_TOTAL 5064
#define WF_ZERO_N 4360    // fsum..tsum zero range (NREP*NF*HD + NREP*64 + 2*NREP)
#define WS_NH_OFF 266240  // align256; newh scratch (fp16)

// ---- LDS layout (ushort units), total 25600 us = 51200 B -> 3 blocks/CU ----
// Strides 136/264: rows are 16B-aligned (r6 lesson: odd strides misalign
// ds_read_b128 -> 2x whole-kernel penalty; bank conflicts are the lesser evil).
#define L_SC    0         // [64][136] us : h bf16
#define L_SH1   8704      // [64][264] us : relu(h1) bf16
#define L_SOF_F 4352      // float idx (us 8704): [64][68] f32 out (overlays sh1)
#define L_SOB   17408     // [64][72] us : out bf16
#define L_ST_F  11008     // [64] f32 t
#define L_SE_F  11072     // [64] f32 e^t
#define L_WSCR_F 11136    // [512] f32 reduction scratch
#define L_TOT   25600

// native bf16 conversion (RNE, same rounding as the old add-shift trick but
// 1 VALU op; compiler fuses pairs into v_cvt_pk_bf16_f32)
__device__ __forceinline__ unsigned short bfc(float f) {
    return __builtin_bit_cast(unsigned short, (__bf16)f);
}
__device__ __forceinline__ float bf2f(unsigned short h) {
    return __builtin_bit_cast(float, (unsigned)h << 16);
}
__device__ __forceinline__ bf16x8 ld8(const unsigned short* p) {
    return __builtin_bit_cast(bf16x8, *(const us8*)p);
}
__device__ __forceinline__ float sigm(float v) {
    return __builtin_amdgcn_rcpf(1.f + __builtin_amdgcn_exp2f(-1.44269504f * v));
}
__device__ __forceinline__ float tanh_fast(float v) {
    return 1.f - 2.f * __builtin_amdgcn_rcpf(1.f + __builtin_amdgcn_exp2f(2.88539008f * v));
}

// ---- per-launch weight conversion fp32 -> bf16 fragment-swizzled ----
// r9: also zeroes the accumulator region (replaces the hipMemsetAsync dispatch)
__global__ __launch_bounds__(256) void convert_kernel(
    const float* __restrict__ x,
    const float* __restrict__ W1a, const float* __restrict__ b1a,
    const float* __restrict__ W2a, const float* __restrict__ b2a,
    const float* __restrict__ W1g, const float* __restrict__ b1g,
    const float* __restrict__ W2g, const float* __restrict__ b2g,
    const float* __restrict__ Wih, const float* __restrict__ Whh,
    unsigned short* __restrict__ wsu, float* __restrict__ wsf)
{
    int i = blockIdx.x * 256 + threadIdx.x;
    if (i < 32768) {                         // W1H, KT=4
        int frag = i >> 9, r = i & 511;
        int lane = r >> 3, e = r & 7;
        int col = (frag >> 2)*16 + (lane & 15);
        int k   = (frag & 3)*32 + (lane >> 4)*8 + e;
        float v = (col < 128) ? W1a[col*192 + 64 + k] : W1g[(col-128)*192 + 64 + k];
        wsu[WS_W1H + i] = bfc(v); return;
    }
    int j = i - 32768;
    if (j < 16384) {                         // W2F, KT=8
        int frag = j >> 9, r = j & 511;
        int lane = r >> 3, e = r & 7;
        int col = (frag >> 3)*16 + (lane & 15);
        int k   = (frag & 7)*32 + (lane >> 4)*8 + e;
        float v = (k < 128) ? W2a[col*128 + k] : -W2g[col*128 + (k-128)];
        wsu[WS_W2F + j] = bfc(v); return;
    }
    j -= 16384;
    if (j < 24576) {                         // WIH (out-cols), KT=2
        int frag = j >> 9, r = j & 511;
        int lane = r >> 3, e = r & 7;
        int col = (frag >> 1)*16 + (lane & 15);
        int k   = (frag & 1)*32 + (lane >> 4)*8 + e;
        wsu[WS_WIH + j] = bfc(Wih[col*65 + k]); return;
    }
    j -= 24576;
    if (j < 49152) {                         // WHH, KT=4
        int frag = j >> 9, r = j & 511;
        int lane = r >> 3, e = r & 7;
        int col = (frag >> 2)*16 + (lane & 15);
        int k   = (frag & 3)*32 + (lane >> 4)*8 + e;
        wsu[WS_WHH + j] = bfc(Whh[col*128 + k]); return;
    }
    j -= 49152;
    if (j < 256) {                           // b1' = b1 + x @ W1x.T  (fp32)
        const float* wr = (j < 128) ? (W1a + j*192) : (W1g + (size_t)(j-128)*192);
        float base = (j < 128) ? b1a[j] : b1g[j-128];
        float dot = 0.f;
        #pragma unroll 8
        for (int k = 0; k < 64; ++k) dot += x[k] * wr[k];
        wsf[WF_B1 + j] = base + dot; return;
    }
    j -= 256;
    if (j < 64)  { wsf[WF_B2 + j] = b2a[j] - b2g[j]; return; }
    j -= 64;
    if (j < 384) { wsf[WF_WT + j] = Wih[j*65 + 64]; return; }
    j -= 384;
    if (j < WF_ZERO_N) { wsf[WF_FSUM + j] = 0.f; return; }   // accumulator zeroing
}

// ---- fused per-cell pipeline, TB=64, 8 waves (r8 structure; native bf16 cvt) ----
// launch_bounds (512,4): VGPR cap 128. Tighter caps spill (r2: WRITE 67->424MB).
__global__ __launch_bounds__(NTH, 4) void fused_cell_kernel(
    const float* __restrict__ hiddens,
    const float* __restrict__ bih, const float* __restrict__ bhh,
    const unsigned short* __restrict__ wsu, const float* __restrict__ wsf,
    unsigned short* __restrict__ nh16, float* __restrict__ nhf,
    float* __restrict__ fsum, float* __restrict__ wsum,
    float* __restrict__ sumexp, float* __restrict__ tsum, int mode)
{
    __shared__ __align__(16) unsigned short sm[L_TOT];
    float* smf = (float*)sm;

    const int tid = threadIdx.x;
    const int cell0 = blockIdx.x * TB;
    const int w = tid >> 6, lane = tid & 63;
    const int q = lane >> 4, cL = lane & 15;
    const int rep = blockIdx.x & (NREP-1);

    // ---- prefetch GEMM1 B frags ----
    bf16x8 pB1[8];
    {
        const unsigned short* wp = wsu + WS_W1H + (w*2)*4*512 + lane*8;
        #pragma unroll
        for (int k = 0; k < 8; ++k) pB1[k] = ld8(wp + k*512);
    }

    // ---- phase 0: stage h bf16 into sc [64][136] ----
    for (int idx = tid; idx < TB*(HD/4); idx += NTH) {
        int c = idx >> 5, k4 = idx & 31;
        float4 v = ((const float4*)hiddens)[(size_t)(cell0+c)*(HD/4) + k4];
        unsigned p0 = (unsigned)bfc(v.x) | ((unsigned)bfc(v.y) << 16);
        unsigned p1 = (unsigned)bfc(v.z) | ((unsigned)bfc(v.w) << 16);
        *(unsigned*)&sm[L_SC + c*136 + k4*4]     = p0;
        *(unsigned*)&sm[L_SC + c*136 + k4*4 + 2] = p1;
    }
    __syncthreads();

    // ---- phase 1: GEMM1 (prefetch GEMM2 B at top) ----
    bf16x8 pB2[8];
    {
        const unsigned short* wp = wsu + WS_W2F + (w & 3)*8*512 + lane*8;
        #pragma unroll
        for (int k = 0; k < 8; ++k) pB2[k] = ld8(wp + k*512);
    }
    #pragma unroll
    for (int ct = 0; ct < 2; ++ct) {
        const int col = w*32 + ct*16 + cL;
        const float bias = wsf[WF_B1 + col];
        f32x4 acc[4];
        #pragma unroll
        for (int m = 0; m < 4; ++m) acc[m] = (f32x4){bias,bias,bias,bias};
        #pragma unroll
        for (int k = 0; k < 4; ++k) {
            bf16x8 B = pB1[ct*4 + k];
            #pragma unroll
            for (int m = 0; m < 4; ++m) {
                bf16x8 A = ld8(&sm[L_SC + (m*16+cL)*136 + k*32 + q*8]);
                acc[m] = MFMA(A, B, acc[m]);
            }
        }
        #pragma unroll
        for (int m = 0; m < 4; ++m)
            #pragma unroll
            for (int r = 0; r < 4; ++r)
                sm[L_SH1 + (m*16+q*4+r)*264 + col] = bfc(fmaxf(acc[m][r], 0.f));
    }
    __syncthreads();

    // ---- phase 2: GEMM2 (prefetch GRU gi B at top) ----
    bf16x8 pGi[6];
    {
        const unsigned short* wiB = wsu + WS_WIH + lane*8;
        #pragma unroll
        for (int k = 0; k < 2; ++k) {
            pGi[k]   = ld8(wiB + ((     w)*2 + k)*512);
            pGi[2+k] = ld8(wiB + (( 8 + w)*2 + k)*512);
            pGi[4+k] = ld8(wiB + ((16 + w)*2 + k)*512);
        }
    }
    f32x4 o0, o1;
    {
        const int Mt0 = (w >> 2)*2, Mt1 = Mt0 + 1;
        const float bias = wsf[WF_B2 + (w & 3)*16 + cL];
        o0 = (f32x4){bias,bias,bias,bias}; o1 = o0;
        #pragma unroll
        for (int k = 0; k < 8; ++k) {
            bf16x8 B  = pB2[k];
            bf16x8 A0 = ld8(&sm[L_SH1 + (Mt0*16+cL)*264 + k*32 + q*8]);
            o0 = MFMA(A0, B, o0);
            bf16x8 A1 = ld8(&sm[L_SH1 + (Mt1*16+cL)*264 + k*32 + q*8]);
            o1 = MFMA(A1, B, o1);
        }
    }
    __syncthreads();   // all sh1 reads done; overlay region now writable

    // ---- phase 2b: out tiles into overlay (sof fp32, sob bf16) ----
    {
        const int col = (w & 3)*16 + cL;
        const int Mt0 = (w >> 2)*2, Mt1 = Mt0 + 1;
        #pragma unroll
        for (int r = 0; r < 4; ++r) {
            int r0 = Mt0*16 + q*4 + r, r1 = Mt1*16 + q*4 + r;
            smf[L_SOF_F + r0*68 + col] = o0[r];
            sm [L_SOB   + r0*72 + col] = bfc(o0[r]);
            smf[L_SOF_F + r1*68 + col] = o1[r];
            sm [L_SOB   + r1*72 + col] = bfc(o1[r]);
        }
    }
    __syncthreads();

    // ---- phase 3: t = mean(out^2), e^t ----
    {
        const int c = tid >> 3, g = tid & 7;
        f32x4 a = *(const f32x4*)&smf[L_SOF_F + c*68 + g*8];
        f32x4 b = *(const f32x4*)&smf[L_SOF_F + c*68 + g*8 + 4];
        float s = a[0]*a[0] + a[1]*a[1] + a[2]*a[2] + a[3]*a[3]
                + b[0]*b[0] + b[1]*b[1] + b[2]*b[2] + b[3]*b[3];
        s += __shfl_xor(s, 1);
        s += __shfl_xor(s, 2);
        s += __shfl_xor(s, 4);
        if (g == 0) {
            float t = s * (1.0f/OUTD);
            smf[L_ST_F + c] = t;
            smf[L_SE_F + c] = __builtin_amdgcn_exp2f(t * 1.44269504f);
        }
    }
    __syncthreads();

    // ---- phase 4: GRU gates, merged 4-M-tile pass ----
    const int fidx = (int)(blockIdx.x >> 8);
    {
        const int j = w*16 + cL;
        const float bR = bih[j]      + bhh[j];
        const float bZ = bih[HD+j]   + bhh[HD+j];
        const float bI = bih[2*HD+j];
        const float bH = bhh[2*HD+j];
        const float wtR = wsf[WF_WT + j];
        const float wtZ = wsf[WF_WT + HD + j];
        const float wtI = wsf[WF_WT + 2*HD + j];
        f32x4 R[4], Z[4], I[4], H[4];
        #pragma unroll
        for (int m = 0; m < 4; ++m) {
            R[m] = (f32x4){bR,bR,bR,bR}; Z[m] = (f32x4){bZ,bZ,bZ,bZ};
            I[m] = (f32x4){bI,bI,bI,bI}; H[m] = (f32x4){bH,bH,bH,bH};
        }
        #pragma unroll
        for (int k = 0; k < 2; ++k) {        // gi: K=64
            bf16x8 Br = pGi[k], Bz = pGi[2+k], Bi = pGi[4+k];
            #pragma unroll
            for (int m = 0; m < 4; ++m) {
                bf16x8 A = ld8(&sm[L_SOB + (m*16+cL)*72 + k*32 + q*8]);
                R[m] = MFMA(A, Br, R[m]);
                Z[m] = MFMA(A, Bz, Z[m]);
                I[m] = MFMA(A, Bi, I[m]);
            }
        }
        const unsigned short* whB = wsu + WS_WHH + lane*8;
        #pragma unroll
        for (int k = 0; k < 4; ++k) {        // gh: K=128
            bf16x8 Br = ld8(whB + ((     w)*4 + k)*512);
            bf16x8 Bz = ld8(whB + (( 8 + w)*4 + k)*512);
            bf16x8 Bn = ld8(whB + ((16 + w)*4 + k)*512);
            #pragma unroll
            for (int m = 0; m < 4; ++m) {
                bf16x8 A = ld8(&sm[L_SC + (m*16+cL)*136 + k*32 + q*8]);
                R[m] = MFMA(A, Br, R[m]);
                Z[m] = MFMA(A, Bz, Z[m]);
                H[m] = MFMA(A, Bn, H[m]);
            }
        }
        float colsum = 0.f;
        #pragma unroll
        for (int m = 0; m < 4; ++m) {
            #pragma unroll
            for (int r = 0; r < 4; ++r) {
                const int row = m*16 + q*4 + r;
                const float tv = smf[L_ST_F + row];
                const float rr = sigm(R[m][r] + tv*wtR);
                const float zz = sigm(Z[m][r] + tv*wtZ);
                const float nn = tanh_fast(I[m][r] + tv*wtI + rr*H[m][r]);
                const float hold = bf2f(sm[L_SC + row*136 + j]);
                const float hv = (1.f - zz)*nn + zz*hold;
                const size_t g = (size_t)(cell0+row)*HD + j;
                if (mode) nh16[g] = __builtin_bit_cast(unsigned short, (_Float16)hv);
                else      nhf[g]  = hv;
                colsum += hv;
            }
        }
        colsum += __shfl_xor(colsum, 16);
        colsum += __shfl_xor(colsum, 32);
        if (q == 0) unsafeAtomicAdd(&fsum[(rep*NF + fidx)*HD + j], colsum);
    }

    // ---- phase 5: softmax-weighted sums ----
    {
        const int col = tid & 63, cg = tid >> 6;
        float wacc = 0.f;
        #pragma unroll
        for (int c8 = 0; c8 < 8; ++c8) {
            const int c = cg*8 + c8;
            wacc += smf[L_SE_F + c] * smf[L_SOF_F + c*68 + col];
        }
        smf[L_WSCR_F + cg*64 + col] = wacc;
    }
    __syncthreads();
    if (tid < 64) {
        float wacc = 0.f;
        #pragma unroll
        for (int g = 0; g < 8; ++g) wacc += smf[L_WSCR_F + g*64 + tid];
        unsafeAtomicAdd(&wsum[rep*64 + tid], wacc);
        float e = smf[L_SE_F + tid];
        float t = smf[L_ST_F + tid];
        #pragma unroll
        for (int d = 1; d < 64; d <<= 1) { e += __shfl_xor(e, d); t += __shfl_xor(t, d); }
        if (tid == 0) { unsafeAtomicAdd(&sumexp[rep], e); unsafeAtomicAdd(&tsum[rep], t); }
    }
}

// ---- faction sync: dst = a*h + b[j]; lane-contiguous (r8) ----
#define TBF 64
__global__ __launch_bounds__(256) void faction_kernel(
    const unsigned short* __restrict__ src16, float* __restrict__ dst,
    const float* __restrict__ fsum, const int* __restrict__ step,
    const float* __restrict__ Wo, const float* __restrict__ bo,
    const float* __restrict__ wsum, const float* __restrict__ sumexp,
    const float* __restrict__ tsum, float* __restrict__ d_out, int mode)
{
    __shared__ float bnon[HD], bdeb[HD];
    const int cell0 = blockIdx.x * TBF;
    const int f = blockIdx.x >> 8;            // 256 blocks per faction
    if (threadIdx.x < HD) {
        const int jc = threadIdx.x;
        float s = 0.f, fm_s = 0.f;
        #pragma unroll
        for (int rr = 0; rr < NREP; ++rr) {
            #pragma unroll
            for (int ff = 0; ff < NF; ++ff) s += fsum[(rr*NF+ff)*HD + jc];
            fm_s += fsum[(rr*NF+f)*HD + jc];
        }
        const float go = s * (1.0f/NCELLS);
        const float fm = fm_s * (1.0f/FS);
        bnon[jc] = 0.15f*fm;
        bdeb[jc] = 0.1275f*fm + 0.15f*go;
    }
    __syncthreads();
    const bool debate = (step[0] > 5) && ((cell0 & (FS-1)) < DC);  // uniform per block
    const float a = debate ? 0.7225f : 0.85f;
    const float* brow = debate ? bdeb : bnon;
    float* drow = dst + (size_t)cell0*HD;
    if (mode) {
        const unsigned short* srow = src16 + (size_t)cell0*HD;
        #pragma unroll
        for (int it = 0; it < (TBF*HD)/256; ++it) {   // 32 iters, lane-contiguous
            const int idx = threadIdx.x + it*256;
            float hv = (float)__builtin_bit_cast(_Float16, srow[idx]);
            drow[idx] = a*hv + brow[idx & 127];
        }
    } else {                                   // fallback: fp32 in-place
        #pragma unroll
        for (int i = 0; i < (TBF*HD)/256; ++i) {
            const int idx = threadIdx.x + i*256;
            drow[idx] = a*drow[idx] + brow[idx & 127];
        }
    }

    if (blockIdx.x == 0 && threadIdx.x < OUTD) {  // fused final head
        const int i = threadIdx.x;
        float seT = 0.f;
        #pragma unroll
        for (int rr = 0; rr < NREP; ++rr) seT += sumexp[rr];
        const float inv = 1.0f / seT;
        const float* wr = Wo + (size_t)i*OUTD;
        float acc = bo[i];
        #pragma unroll 8
        for (int jj = 0; jj < OUTD; ++jj) {
            float wv = wsum[jj] + wsum[64+jj] + wsum[128+jj] + wsum[192+jj];
            acc += (wv*inv) * wr[jj];
        }
        d_out[i] = acc;
        if (i == 0) {
            float tT = 0.f;
            #pragma unroll
            for (int rr = 0; rr < NREP; ++rr) tT += tsum[rr];
            d_out[OUTD] = tT * (1.0f/NCELLS);
        }
    }
}

extern "C" void kernel_launch(void* const* d_in, const int* in_sizes, int n_in,
                              void* d_out, int out_size, void* d_ws, size_t ws_size,
                              hipStream_t stream)
{
    const float* x   = (const float*)d_in[0];
    const float* hid = (const float*)d_in[1];
    const float* W1a = (const float*)d_in[2];
    const float* b1a = (const float*)d_in[3];
    const float* W2a = (const float*)d_in[4];
    const float* b2a = (const float*)d_in[5];
    const float* W1g = (const float*)d_in[6];
    const float* b1g = (const float*)d_in[7];
    const float* W2g = (const float*)d_in[8];
    const float* b2g = (const float*)d_in[9];
    const float* Wih = (const float*)d_in[10];
    const float* Whh = (const float*)d_in[11];
    const float* bih = (const float*)d_in[12];
    const float* bhh = (const float*)d_in[13];
    const float* Wo  = (const float*)d_in[14];
    const float* bo  = (const float*)d_in[15];
    const int*  step = (const int*)d_in[16];

    float* out  = (float*)d_out;
    float* newh_out = out + (OUTD + 1);

    unsigned short* wsu = (unsigned short*)d_ws;
    float* wsf = (float*)(wsu + WS_U_TOTAL);
    float* fsum   = wsf + WF_FSUM;
    float* wsum   = wsf + WF_WSUM;
    float* sumexp = wsf + WF_SE;
    float* tsum   = wsf + WF_TS;

    const size_t need = (size_t)WS_NH_OFF + (size_t)NT*sizeof(unsigned short);
    const int mode = (ws_size >= need) ? 1 : 0;
    unsigned short* nh16 = (unsigned short*)((char*)d_ws + WS_NH_OFF);

    // convert elements: 123584 weights/biases + 4360 accumulator zeros = 127944
    convert_kernel<<<(127944 + 255)/256, 256, 0, stream>>>(
        x, W1a, b1a, W2a, b2a, W1g, b1g, W2g, b2g, Wih, Whh, wsu, wsf);

    fused_cell_kernel<<<NBLK, NTH, 0, stream>>>(
        hid, bih, bhh, wsu, wsf, nh16, newh_out, fsum, wsum, sumexp, tsum, mode);

    faction_kernel<<<NCELLS/TBF, 256, 0, stream>>>(
        nh16, newh_out, fsum, step, Wo, bo, wsum, sumexp, tsum, out, mode);
}